// Round 8
// baseline (178.279 us; speedup 1.0000x reference)
//
#include <hip/hip_runtime.h>
#include <math.h>

#define BATCH 16
#define S_LEN 4096
#define D2c   256
#define D8c   1024
#define GNUM  24
#define QNUM  48
#define WINc  12
#define NCA   128   // att streaming blocks per batch (32 rows each)
#define NCM   32    // mod streaming blocks per batch (128 rows, 4 groups x 32)
#define NSB   (BATCH * GNUM)        // 384 bidaf-S blocks
#define NWB   (BATCH * (GNUM - 1))  // 368 window blocks
#define N_ATT (BATCH * NCA)         // 2048
#define N_MOD (BATCH * NCM)         // 512

typedef float floatx4 __attribute__((ext_vector_type(4)));

__device__ inline float4 f4max(float4 a, float4 b) {
    return make_float4(fmaxf(a.x,b.x), fmaxf(a.y,b.y), fmaxf(a.z,b.z), fmaxf(a.w,b.w));
}
__device__ inline float4 f4add(float4 a, float4 b) {
    return make_float4(a.x+b.x, a.y+b.y, a.z+b.z, a.w+b.w);
}
__device__ inline float4 f4scale(float4 a, float s) {
    return make_float4(a.x*s, a.y*s, a.z*s, a.w*s);
}
__device__ inline float4 f4mul(float4 a, float4 b) {
    return make_float4(a.x*b.x, a.y*b.y, a.z*b.z, a.w*b.w);
}
__device__ inline float dot4(float4 a, float4 b) {
    return a.x*b.x + a.y*b.y + a.z*b.z + a.w*b.w;
}
__device__ inline float4 ldnt4(const float4* p) {
    const floatx4 v = __builtin_nontemporal_load(reinterpret_cast<const floatx4*>(p));
    return make_float4(v.x, v.y, v.z, v.w);
}
// order-preserving float<->uint mapping for atomicMax
__device__ inline unsigned fmap(float x) {
    unsigned u = __float_as_uint(x);
    return (u >> 31) ? ~u : (u | 0x80000000u);
}
__device__ inline float funmap(unsigned u) {
    return (u >> 31) ? __uint_as_float(u & 0x7FFFFFFFu) : __uint_as_float(~u);
}
// 64-lane butterfly sum (result in all lanes)
__device__ inline float wredsum(float v) {
    #pragma unroll
    for (int m = 32; m > 0; m >>= 1) v += __shfl_xor(v, m, 64);
    return v;
}

struct SSh {                       // bidaf-S blocks (~4.2 KB)
    float c[D2c];
    float pa[4][QNUM];
    float pb[4][QNUM];
    float pm[8][32];
    float p0[2][64];
    int   gids[GNUM];
};
struct WSh {                       // window blocks
    float wmf[32];
    float red[256];
    float rden;
};
union ShU { SSh s; WSh w; };

// ---------------------------------------------------------------------------
// K1 block layout (streaming first so all CUs stream from t=0):
//   [0, N_ATT)                      att stream, 32 rows x 1024 ch
//   [N_ATT, N_ATT+N_MOD)            mod stream, 128 rows x 256 ch
//   [.., +NWB)                      window pooling (g>=1)
//   [.., +NSB)                      bidaf-S
// ---------------------------------------------------------------------------
__global__ __launch_bounds__(256) void k1_kernel(
    const float* __restrict__ att, const float* __restrict__ mod,
    const float* __restrict__ q_enc,
    const int* __restrict__ gap_idx, const int* __restrict__ mask,
    const float* __restrict__ c_w, const float* __restrict__ cq_w,
    const float* __restrict__ W_att2, const float* __restrict__ W_att_s2,
    const float* __restrict__ W_att, const float* __restrict__ W_mod,
    const float* __restrict__ W_att_s, const float* __restrict__ W_mod_s,
    unsigned* __restrict__ attMaxU, unsigned* __restrict__ modMaxU,
    float* __restrict__ sumdots,
    float* __restrict__ s2v_ws, float* __restrict__ vv_ws,
    float* __restrict__ m_ws, float* __restrict__ s0uc_ws,
    float* __restrict__ winpart)
{
    __shared__ ShU sh;
    const int tid = threadIdx.x;
    const int bid = blockIdx.x;

    if (bid < N_ATT) {
        // ---------------- att stream: 32 rows x 1024 ch --------------------
        const int b = bid >> 7, ch = bid & 127;
        const float4* base = reinterpret_cast<const float4*>(att)
                             + ((size_t)b * S_LEN + ch * 32) * (D8c/4) + tid;
        float4 mx = make_float4(-INFINITY, -INFINITY, -INFINITY, -INFINITY);
        float4 sm = make_float4(0.f, 0.f, 0.f, 0.f);
        #pragma unroll 16
        for (int r = 0; r < 32; ++r) {
            const float4 v = ldnt4(base + (size_t)r * (D8c/4));
            mx = f4max(mx, v);
            sm = f4add(sm, v);
        }
        unsigned* amax = attMaxU + (size_t)b * D8c + tid * 4;
        atomicMax(&amax[0], fmap(mx.x));
        atomicMax(&amax[1], fmap(mx.y));
        atomicMax(&amax[2], fmap(mx.z));
        atomicMax(&amax[3], fmap(mx.w));
        // distributed avg-dot, per-wave shuffle reduce + one atomicAdd
        const float4 wsum = reinterpret_cast<const float4*>(W_att_s)[2*(D8c/4) + tid];
        const float p = wredsum(dot4(sm, wsum));
        if ((tid & 63) == 0) atomicAdd(&sumdots[b], p);
    } else if (bid < N_ATT + N_MOD) {
        // ---------------- mod stream: 128 rows x 256 ch --------------------
        const int mb = bid - N_ATT;
        const int b = mb >> 5, ch = mb & 31;
        const int rg = tid >> 6, c4i = tid & 63;
        const float4* base = reinterpret_cast<const float4*>(mod)
                             + ((size_t)b * S_LEN + ch * 128 + rg * 32) * (D2c/4) + c4i;
        float4 mx = make_float4(-INFINITY, -INFINITY, -INFINITY, -INFINITY);
        float4 sm = make_float4(0.f, 0.f, 0.f, 0.f);
        #pragma unroll 16
        for (int r = 0; r < 32; ++r) {
            const float4 v = ldnt4(base + (size_t)r * (D2c/4));
            mx = f4max(mx, v);
            sm = f4add(sm, v);
        }
        unsigned* mmax = modMaxU + (size_t)b * D2c + c4i * 4;
        atomicMax(&mmax[0], fmap(mx.x));
        atomicMax(&mmax[1], fmap(mx.y));
        atomicMax(&mmax[2], fmap(mx.z));
        atomicMax(&mmax[3], fmap(mx.w));
        const float4 wsum = reinterpret_cast<const float4*>(W_mod_s)[2*(D2c/4) + c4i];
        const float p = wredsum(dot4(sm, wsum));
        if ((tid & 63) == 0) atomicAdd(&sumdots[BATCH + b], p);
    } else if (bid < N_ATT + N_MOD + NWB) {
        // ---------------- window blocks (g>=1) ---------------------------
        const int wb = bid - N_ATT - N_MOD;
        const int b = wb / (GNUM - 1), g = wb % (GNUM - 1) + 1;
        const int gid = gap_idx[b * GNUM + g];
        const int lo = (gid - WINc > 0) ? gid - WINc : 0;
        const int hi = (gid + WINc < S_LEN - 1) ? gid + WINc : S_LEN - 1;
        const int n = hi - lo + 1;           // <= 25
        const int gsel = gid - lo;

        if (tid < 32)
            sh.w.wmf[tid] = (tid < n && mask[b * S_LEN + lo + tid] != 0) ? 1.f : 0.f;
        __syncthreads();
        if (tid == 0) {
            float d = 0.f;
            for (int i = 0; i < 25; ++i) d += sh.w.wmf[i];
            sh.w.rden = 1.f / d;
        }
        __syncthreads();
        const float rden = sh.w.rden;

        const float4* Wa4 = reinterpret_cast<const float4*>(W_att);
        const float4* Wm4 = reinterpret_cast<const float4*>(W_mod);

        float acc = 0.f;
        {
            const float4* base = reinterpret_cast<const float4*>(att)
                                 + ((size_t)b * S_LEN + lo) * (D8c/4) + tid;
            float4 mx = make_float4(0.f, 0.f, 0.f, 0.f);  // zero-clamped max
            float4 sm = make_float4(0.f, 0.f, 0.f, 0.f);
            float4 gv = make_float4(0.f, 0.f, 0.f, 0.f);
            #pragma unroll 5
            for (int i = 0; i < 25; ++i) {
                const int off = (i < n) ? i : 0;
                const float4 v = base[(size_t)off * (D8c/4)];
                const float w = sh.w.wmf[i];
                const float4 vm = f4scale(v, w);
                mx = f4max(mx, vm);
                sm = f4add(sm, vm);
                if (i == gsel) gv = v;
            }
            acc += dot4(gv, Wa4[tid]);
            acc += dot4(mx, Wa4[(D8c/4) + tid]) + dot4(sm, Wa4[2*(D8c/4) + tid]) * rden;
        }
        if (tid < D2c/4) {
            const float4* base = reinterpret_cast<const float4*>(mod)
                                 + ((size_t)b * S_LEN + lo) * (D2c/4) + tid;
            float4 mx = make_float4(0.f, 0.f, 0.f, 0.f);
            float4 sm = make_float4(0.f, 0.f, 0.f, 0.f);
            float4 gv = make_float4(0.f, 0.f, 0.f, 0.f);
            #pragma unroll 5
            for (int i = 0; i < 25; ++i) {
                const int off = (i < n) ? i : 0;
                const float4 v = base[(size_t)off * (D2c/4)];
                const float w = sh.w.wmf[i];
                const float4 vm = f4scale(v, w);
                mx = f4max(mx, vm);
                sm = f4add(sm, vm);
                if (i == gsel) gv = v;
            }
            acc += dot4(gv, Wm4[tid]);
            acc += dot4(mx, Wm4[(D2c/4) + tid]) + dot4(sm, Wm4[2*(D2c/4) + tid]) * rden;
        }

        sh.w.red[tid] = acc;
        __syncthreads();
        for (int off = 128; off > 0; off >>= 1) {
            if (tid < off) sh.w.red[tid] += sh.w.red[tid + off];
            __syncthreads();
        }
        if (tid == 0) winpart[b * GNUM + g] = sh.w.red[0];
    } else {
        // ---------------- bidaf-S: one (b,g) per block --------------------
        const int sb = bid - N_ATT - N_MOD - NWB;
        const int b = sb / GNUM, g = sb % GNUM;
        const float4* mod4 = reinterpret_cast<const float4*>(mod);
        const float4* q4   = reinterpret_cast<const float4*>(q_enc);
        const float4* Wsel = reinterpret_cast<const float4*>((g == 0) ? W_att_s2 : W_att2);

        if (tid < GNUM) sh.s.gids[tid] = gap_idx[b * GNUM + tid];
        __syncthreads();
        const int gid = sh.s.gids[g];
        if (tid < 64)
            reinterpret_cast<float4*>(sh.s.c)[tid] = mod4[((size_t)b * S_LEN + gid) * (D2c/4) + tid];
        __syncthreads();
        const float4* c4 = reinterpret_cast<const float4*>(sh.s.c);

        if (tid < 64) {
            sh.s.p0[0][tid] = dot4(c4[tid], reinterpret_cast<const float4*>(c_w)[tid]);
        } else if (tid < 128) {
            sh.s.p0[1][tid - 64] = dot4(c4[tid - 64], Wsel[tid - 64]);
        }

        // s2 / v partials: thread (q, p), p covers 64 channels (16 float4)
        {
            const int q = tid & 63, p = tid >> 6;
            if (q < QNUM) {
                const float4* qr = q4 + ((size_t)b * QNUM + q) * (D2c/4) + p * 16;
                const float4* cl = c4 + p * 16;
                const float4* cw = reinterpret_cast<const float4*>(cq_w) + p * 16;
                const float4* wa = Wsel + 2 * (D2c/4) + p * 16;
                float a_s2 = 0.f, a_v = 0.f;
                #pragma unroll
                for (int i = 0; i < 16; ++i) {
                    const float4 cq = f4mul(cl[i], qr[i]);
                    a_s2 += dot4(cq, cw[i]);
                    a_v  += dot4(cq, wa[i]);
                }
                sh.s.pa[p][q] = a_s2;
                sh.s.pb[p][q] = a_v;
            }
        }

        // m partials: thread (k, p8), p8 covers 32 channels (8 float4)
        {
            const int k = tid & 31, p8 = tid >> 5;
            if (k < GNUM) {
                const float4* kr = mod4 + ((size_t)b * S_LEN + sh.s.gids[k]) * (D2c/4) + p8 * 8;
                const float4* cl = c4 + p8 * 8;
                const float4* wb = Wsel + 3 * (D2c/4) + p8 * 8;
                float am = 0.f;
                #pragma unroll
                for (int i = 0; i < 8; ++i) {
                    const float4 t = f4mul(cl[i], kr[i]);
                    am += dot4(t, wb[i]);
                }
                sh.s.pm[p8][k] = am;
            }
        }
        __syncthreads();

        if (tid < QNUM) {
            const float s2 = sh.s.pa[0][tid] + sh.s.pa[1][tid] + sh.s.pa[2][tid] + sh.s.pa[3][tid];
            const float v  = sh.s.pb[0][tid] + sh.s.pb[1][tid] + sh.s.pb[2][tid] + sh.s.pb[3][tid];
            s2v_ws[(size_t)sb * QNUM + tid] = s2;
            vv_ws [(size_t)sb * QNUM + tid] = v;
        } else if (tid >= 64 && tid < 64 + GNUM) {
            const int k = tid - 64;
            float m = 0.f;
            #pragma unroll
            for (int p8 = 0; p8 < 8; ++p8) m += sh.s.pm[p8][k];
            m_ws[(size_t)sb * GNUM + k] = m;
        } else if (tid == 62) {
            float a = 0.f;
            for (int i = 0; i < 64; ++i) a += sh.s.p0[0][i];
            s0uc_ws[(size_t)sb * 2 + 0] = a;
        } else if (tid == 63) {
            float a = 0.f;
            for (int i = 0; i < 64; ++i) a += sh.s.p0[1][i];
            s0uc_ws[(size_t)sb * 2 + 1] = a;
        }
    }
}

// ---------------------------------------------------------------------------
// K2: per-batch: q-side dots, softmaxes, att2, tiny g0 combine, output.
// ---------------------------------------------------------------------------
__global__ __launch_bounds__(256) void k2_kernel(
    const float* __restrict__ att, const float* __restrict__ mod,
    const float* __restrict__ q_enc,
    const int* __restrict__ gap_idx, const int* __restrict__ mask,
    const int* __restrict__ q_mask,
    const float* __restrict__ q_w, const float* __restrict__ att_bias,
    const float* __restrict__ W_att2, const float* __restrict__ W_att_s2,
    const float* __restrict__ W_att_s, const float* __restrict__ W_mod_s,
    const float* __restrict__ b_att, const float* __restrict__ b_mod,
    const float* __restrict__ b_att2,
    const float* __restrict__ b_att_s, const float* __restrict__ b_mod_s,
    const float* __restrict__ b_att_s2,
    const unsigned* __restrict__ attMaxU, const unsigned* __restrict__ modMaxU,
    const float* __restrict__ sumdots,
    const float* __restrict__ s2v_ws, const float* __restrict__ vv_ws,
    const float* __restrict__ m_ws, const float* __restrict__ s0uc_ws,
    const float* __restrict__ winpart,
    float* __restrict__ out)
{
    const int b = blockIdx.x;
    const int tid = threadIdx.x;

    __shared__ float s_sh[GNUM][QNUM];
    __shared__ float sm1[GNUM][QNUM];
    __shared__ float sm2[GNUM][QNUM];
    __shared__ float ssm[GNUM][GNUM];
    __shared__ float pq[3][4][QNUM];
    __shared__ float s1[QNUM], u0[QNUM], u1[QNUM];
    __shared__ float s0g[GNUM], ucg[GNUM], att2v[GNUM];
    __shared__ float red[256];
    __shared__ float rdensh;

    // ---- Phase Q: s1/u0/u1 via (q, d-quarter) partials -------------------
    {
        const int q = tid & 63, p = tid >> 6;
        if (q < QNUM) {
            const float4* qr = reinterpret_cast<const float4*>(q_enc)
                               + ((size_t)b * QNUM + q) * (D2c/4) + p * 16;
            const float4* w1 = reinterpret_cast<const float4*>(q_w) + p * 16;
            const float4* w2 = reinterpret_cast<const float4*>(W_att_s2) + (D2c/4) + p * 16;
            const float4* w3 = reinterpret_cast<const float4*>(W_att2)   + (D2c/4) + p * 16;
            float a1 = 0.f, a2 = 0.f, a3 = 0.f;
            #pragma unroll
            for (int i = 0; i < 16; ++i) {
                const float4 v = qr[i];
                a1 += dot4(v, w1[i]);
                a2 += dot4(v, w2[i]);
                a3 += dot4(v, w3[i]);
            }
            pq[0][p][q] = a1; pq[1][p][q] = a2; pq[2][p][q] = a3;
        }
    }
    if (tid < GNUM) {
        s0g[tid] = s0uc_ws[((size_t)b * GNUM + tid) * 2 + 0];
        ucg[tid] = s0uc_ws[((size_t)b * GNUM + tid) * 2 + 1];
    }
    __syncthreads();
    if (tid < QNUM) {
        s1[tid] = pq[0][0][tid] + pq[0][1][tid] + pq[0][2][tid] + pq[0][3][tid];
        u0[tid] = pq[1][0][tid] + pq[1][1][tid] + pq[1][2][tid] + pq[1][3][tid];
        u1[tid] = pq[2][0][tid] + pq[2][1][tid] + pq[2][2][tid] + pq[2][3][tid];
    }
    __syncthreads();

    // ---- build s ----------------------------------------------------------
    const float bias = att_bias[0];
    for (int i = tid; i < GNUM * QNUM; i += 256) {
        const int g = i / QNUM, q = i % QNUM;
        s_sh[g][q] = s0g[g] + s1[q] + s2v_ws[((size_t)b * GNUM + g) * QNUM + q] + bias;
    }
    __syncthreads();

    // ---- softmaxes --------------------------------------------------------
    if (tid < QNUM) {
        const int q = tid;
        float mxv = -1e30f;
        for (int g = 0; g < GNUM; ++g) mxv = fmaxf(mxv, s_sh[g][q]);
        float sum = 0.f;
        for (int g = 0; g < GNUM; ++g) {
            const float e = __expf(s_sh[g][q] - mxv);
            sm2[g][q] = e;
            sum += e;
        }
        const float inv = 1.f / sum;
        for (int g = 0; g < GNUM; ++g) sm2[g][q] *= inv;
    } else if (tid >= 64 && tid < 64 + GNUM) {
        const int g = tid - 64;
        float mxv = -1e30f;
        for (int q = 0; q < QNUM; ++q)
            if (q_mask[b * QNUM + q]) mxv = fmaxf(mxv, s_sh[g][q]);
        float sum = 0.f;
        for (int q = 0; q < QNUM; ++q) {
            const float e = q_mask[b * QNUM + q] ? __expf(s_sh[g][q] - mxv) : 0.f;
            sm1[g][q] = e;
            sum += e;
        }
        const float inv = 1.f / sum;
        for (int q = 0; q < QNUM; ++q) sm1[g][q] *= inv;
    }
    __syncthreads();

    // ---- ss*m: thread-per-(g,k) -------------------------------------------
    for (int i = tid; i < GNUM * GNUM; i += 256) {
        const int g = i / GNUM, k = i % GNUM;
        float t = 0.f;
        for (int q = 0; q < QNUM; ++q) t += sm1[g][q] * sm2[k][q];
        ssm[g][k] = t * m_ws[((size_t)b * GNUM + g) * GNUM + k];
    }
    __syncthreads();

    // ---- att2 logit per g ---------------------------------------------------
    if (tid < GNUM) {
        const int g = tid;
        const float* uu = (g == 0) ? u0 : u1;
        float acc = ucg[g];
        for (int q = 0; q < QNUM; ++q)
            acc += sm1[g][q] * (uu[q] + vv_ws[((size_t)b * GNUM + g) * QNUM + q]);
        for (int k = 0; k < GNUM; ++k) acc += ssm[g][k];
        att2v[g] = acc;
    }

    // ---- Part 2: denom0 + tiny g0 combine + output --------------------------
    float cnt = 0.f;
    for (int s = tid; s < S_LEN; s += 256) cnt += (mask[b * S_LEN + s] != 0) ? 1.f : 0.f;
    red[tid] = cnt;
    __syncthreads();
    for (int off = 128; off > 0; off >>= 1) {
        if (tid < off) red[tid] += red[tid + off];
        __syncthreads();
    }
    if (tid == 0) rdensh = 1.f / red[0];
    __syncthreads();
    const float rden0 = rdensh;

    const int gid0 = gap_idx[b * GNUM];
    const float4* Wa4 = reinterpret_cast<const float4*>(W_att_s);
    const float4* Wm4 = reinterpret_cast<const float4*>(W_mod_s);

    float acc = 0.f;
    {
        const uint4 mu = reinterpret_cast<const uint4*>(attMaxU + (size_t)b * D8c)[tid];
        const float4 mx = make_float4(funmap(mu.x), funmap(mu.y), funmap(mu.z), funmap(mu.w));
        acc += dot4(mx, Wa4[(D8c/4) + tid]);
        const float4 ar = reinterpret_cast<const float4*>(att)[((size_t)b * S_LEN + gid0) * (D8c/4) + tid];
        acc += dot4(ar, Wa4[tid]);
    }
    if (tid < D2c/4) {
        const uint4 mu = reinterpret_cast<const uint4*>(modMaxU + (size_t)b * D2c)[tid];
        const float4 mx = make_float4(funmap(mu.x), funmap(mu.y), funmap(mu.z), funmap(mu.w));
        acc += dot4(mx, Wm4[(D2c/4) + tid]);
        const float4 mr = reinterpret_cast<const float4*>(mod)[((size_t)b * S_LEN + gid0) * (D2c/4) + tid];
        acc += dot4(mr, Wm4[tid]);
    }

    __syncthreads();
    red[tid] = acc;
    __syncthreads();
    for (int off = 128; off > 0; off >>= 1) {
        if (tid < off) red[tid] += red[tid + off];
        __syncthreads();
    }
    if (tid == 0) {
        const float avgpart = (sumdots[b] + sumdots[BATCH + b]) * rden0;
        out[b * GNUM] = red[0] + avgpart + att2v[0] + b_att_s[0] + b_mod_s[0] + b_att_s2[0];
    } else if (tid < GNUM) {
        out[b * GNUM + tid] = winpart[b * GNUM + tid] + att2v[tid]
                              + b_att[0] + b_mod[0] + b_att2[0];
    }
}

// ---------------------------------------------------------------------------
extern "C" void kernel_launch(void* const* d_in, const int* in_sizes, int n_in,
                              void* d_out, int out_size, void* d_ws, size_t ws_size,
                              hipStream_t stream)
{
    const float* att      = (const float*)d_in[0];
    const float* mod      = (const float*)d_in[1];
    const float* q_enc    = (const float*)d_in[2];
    const int*   gap_idx  = (const int*)  d_in[3];
    const int*   mask     = (const int*)  d_in[4];
    const int*   q_mask   = (const int*)  d_in[5];
    const float* c_w      = (const float*)d_in[6];
    const float* q_w      = (const float*)d_in[7];
    const float* cq_w     = (const float*)d_in[8];
    const float* att_bias = (const float*)d_in[9];
    const float* W_att    = (const float*)d_in[10];
    const float* b_att    = (const float*)d_in[11];
    const float* W_mod    = (const float*)d_in[12];
    const float* b_mod    = (const float*)d_in[13];
    const float* W_att2   = (const float*)d_in[14];
    const float* b_att2   = (const float*)d_in[15];
    const float* W_att_s  = (const float*)d_in[16];
    const float* b_att_s  = (const float*)d_in[17];
    const float* W_mod_s  = (const float*)d_in[18];
    const float* b_mod_s  = (const float*)d_in[19];
    const float* W_att_s2 = (const float*)d_in[20];
    const float* b_att_s2 = (const float*)d_in[21];

    float* out = (float*)d_out;

    // ws layout: atomic region first (zeroed every call), then k1->k2 arrays
    unsigned* attMaxU = (unsigned*)d_ws;                              // 16*1024
    unsigned* modMaxU = attMaxU + (size_t)BATCH * D8c;                // 16*256
    float*    sumdots = (float*)(modMaxU + (size_t)BATCH * D2c);      // 32
    float*    s2v_ws  = sumdots + 32;                                 // 384*48
    float*    vv_ws   = s2v_ws + (size_t)NSB * QNUM;                  // 384*48
    float*    m_ws    = vv_ws  + (size_t)NSB * QNUM;                  // 384*24
    float*    s0uc_ws = m_ws   + (size_t)NSB * GNUM;                  // 768
    float*    winpart = s0uc_ws + (size_t)NSB * 2;                    // 384

    const size_t atomicBytes = ((size_t)BATCH * D8c + (size_t)BATCH * D2c + 32) * 4;
    (void)hipMemsetAsync(d_ws, 0, atomicBytes, stream);  // mapped-max sentinel + 0.f sums

    const int grid1 = N_ATT + N_MOD + NWB + NSB;                      // 3312

    k1_kernel<<<grid1, 256, 0, stream>>>(
        att, mod, q_enc, gap_idx, mask,
        c_w, cq_w, W_att2, W_att_s2, W_att, W_mod, W_att_s, W_mod_s,
        attMaxU, modMaxU, sumdots,
        s2v_ws, vv_ws, m_ws, s0uc_ws, winpart);

    k2_kernel<<<BATCH, 256, 0, stream>>>(
        att, mod, q_enc, gap_idx, mask, q_mask,
        q_w, att_bias, W_att2, W_att_s2,
        W_att_s, W_mod_s, b_att, b_mod, b_att2,
        b_att_s, b_mod_s, b_att_s2,
        attMaxU, modMaxU, sumdots,
        s2v_ws, vv_ws, m_ws, s0uc_ws, winpart, out);
}

// Round 9
// 100.667 us; speedup vs baseline: 1.7710x; 1.7710x over previous
//
#include <hip/hip_runtime.h>
#include <math.h>

#define BATCH 16
#define S_LEN 4096
#define D2c   256
#define D8c   1024
#define GNUM  24
#define QNUM  48
#define WINc  12
#define NCA   64    // att streaming blocks per batch (64 rows each)
#define NCM   16    // mod streaming blocks per batch (256 rows, 4 groups x 64)
#define NSB   (BATCH * GNUM)        // 384 bidaf-S blocks
#define NWB   (BATCH * (GNUM - 1))  // 368 window blocks

__device__ inline float4 f4max(float4 a, float4 b) {
    return make_float4(fmaxf(a.x,b.x), fmaxf(a.y,b.y), fmaxf(a.z,b.z), fmaxf(a.w,b.w));
}
__device__ inline float4 f4add(float4 a, float4 b) {
    return make_float4(a.x+b.x, a.y+b.y, a.z+b.z, a.w+b.w);
}
__device__ inline float4 f4scale(float4 a, float s) {
    return make_float4(a.x*s, a.y*s, a.z*s, a.w*s);
}
__device__ inline float4 f4mul(float4 a, float4 b) {
    return make_float4(a.x*b.x, a.y*b.y, a.z*b.z, a.w*b.w);
}
__device__ inline float dot4(float4 a, float4 b) {
    return a.x*b.x + a.y*b.y + a.z*b.z + a.w*b.w;
}
// order-preserving float<->uint mapping for atomicMax
__device__ inline unsigned fmap(float x) {
    unsigned u = __float_as_uint(x);
    return (u >> 31) ? ~u : (u | 0x80000000u);
}
__device__ inline float funmap(unsigned u) {
    return (u >> 31) ? __uint_as_float(u & 0x7FFFFFFFu) : __uint_as_float(~u);
}

struct SSh {                       // bidaf-S blocks (~4.2 KB)
    float c[D2c];
    float pa[4][QNUM];
    float pb[4][QNUM];
    float pm[8][32];
    float p0[2][64];
    int   gids[GNUM];
};
struct WSh {                       // window / streaming blocks
    float wmf[32];
    float red[256];
    float rden;
};
union ShU { SSh s; WSh w; };

// ---------------------------------------------------------------------------
// K1: bidaf-S (384) + window (368) + att stream (1024) + mod stream (256).
// Streaming pools publish via per-channel atomicMax (mapped uints) and one
// atomicAdd per block (distributed avg-dot). Streaming loops use two
// independent load chains (rows r and r+32) for memory-level parallelism.
// ---------------------------------------------------------------------------
__global__ __launch_bounds__(256) void k1_kernel(
    const float* __restrict__ att, const float* __restrict__ mod,
    const float* __restrict__ q_enc,
    const int* __restrict__ gap_idx, const int* __restrict__ mask,
    const float* __restrict__ c_w, const float* __restrict__ cq_w,
    const float* __restrict__ W_att2, const float* __restrict__ W_att_s2,
    const float* __restrict__ W_att, const float* __restrict__ W_mod,
    const float* __restrict__ W_att_s, const float* __restrict__ W_mod_s,
    unsigned* __restrict__ attMaxU, unsigned* __restrict__ modMaxU,
    float* __restrict__ sumdots,
    float* __restrict__ s2v_ws, float* __restrict__ vv_ws,
    float* __restrict__ m_ws, float* __restrict__ s0uc_ws,
    float* __restrict__ winpart)
{
    __shared__ ShU sh;
    const int tid = threadIdx.x;
    const int bid = blockIdx.x;

    if (bid < NSB) {
        // ---------------- bidaf-S: one (b,g) per block --------------------
        const int b = bid / GNUM, g = bid % GNUM;
        const float4* mod4 = reinterpret_cast<const float4*>(mod);
        const float4* q4   = reinterpret_cast<const float4*>(q_enc);
        const float4* Wsel = reinterpret_cast<const float4*>((g == 0) ? W_att_s2 : W_att2);

        if (tid < GNUM) sh.s.gids[tid] = gap_idx[b * GNUM + tid];
        __syncthreads();
        const int gid = sh.s.gids[g];
        if (tid < 64)
            reinterpret_cast<float4*>(sh.s.c)[tid] = mod4[((size_t)b * S_LEN + gid) * (D2c/4) + tid];
        __syncthreads();
        const float4* c4 = reinterpret_cast<const float4*>(sh.s.c);

        if (tid < 64) {
            sh.s.p0[0][tid] = dot4(c4[tid], reinterpret_cast<const float4*>(c_w)[tid]);
        } else if (tid < 128) {
            sh.s.p0[1][tid - 64] = dot4(c4[tid - 64], Wsel[tid - 64]);
        }

        // s2 / v partials: thread (q, p), p covers 64 channels (16 float4)
        {
            const int q = tid & 63, p = tid >> 6;
            if (q < QNUM) {
                const float4* qr = q4 + ((size_t)b * QNUM + q) * (D2c/4) + p * 16;
                const float4* cl = c4 + p * 16;
                const float4* cw = reinterpret_cast<const float4*>(cq_w) + p * 16;
                const float4* wa = Wsel + 2 * (D2c/4) + p * 16;
                float a_s2 = 0.f, a_v = 0.f;
                #pragma unroll
                for (int i = 0; i < 16; ++i) {
                    const float4 cq = f4mul(cl[i], qr[i]);
                    a_s2 += dot4(cq, cw[i]);
                    a_v  += dot4(cq, wa[i]);
                }
                sh.s.pa[p][q] = a_s2;
                sh.s.pb[p][q] = a_v;
            }
        }

        // m partials: thread (k, p8), p8 covers 32 channels (8 float4)
        {
            const int k = tid & 31, p8 = tid >> 5;
            if (k < GNUM) {
                const float4* kr = mod4 + ((size_t)b * S_LEN + sh.s.gids[k]) * (D2c/4) + p8 * 8;
                const float4* cl = c4 + p8 * 8;
                const float4* wb = Wsel + 3 * (D2c/4) + p8 * 8;
                float am = 0.f;
                #pragma unroll
                for (int i = 0; i < 8; ++i) {
                    const float4 t = f4mul(cl[i], kr[i]);
                    am += dot4(t, wb[i]);
                }
                sh.s.pm[p8][k] = am;
            }
        }
        __syncthreads();

        if (tid < QNUM) {
            const float s2 = sh.s.pa[0][tid] + sh.s.pa[1][tid] + sh.s.pa[2][tid] + sh.s.pa[3][tid];
            const float v  = sh.s.pb[0][tid] + sh.s.pb[1][tid] + sh.s.pb[2][tid] + sh.s.pb[3][tid];
            s2v_ws[(size_t)bid * QNUM + tid] = s2;
            vv_ws [(size_t)bid * QNUM + tid] = v;
        } else if (tid >= 64 && tid < 64 + GNUM) {
            const int k = tid - 64;
            float m = 0.f;
            #pragma unroll
            for (int p8 = 0; p8 < 8; ++p8) m += sh.s.pm[p8][k];
            m_ws[(size_t)bid * GNUM + k] = m;
        } else if (tid == 62) {
            float a = 0.f;
            for (int i = 0; i < 64; ++i) a += sh.s.p0[0][i];
            s0uc_ws[(size_t)bid * 2 + 0] = a;
        } else if (tid == 63) {
            float a = 0.f;
            for (int i = 0; i < 64; ++i) a += sh.s.p0[1][i];
            s0uc_ws[(size_t)bid * 2 + 1] = a;
        }
    } else if (bid < NSB + NWB) {
        // ---------------- window blocks (g>=1) ---------------------------
        const int wb = bid - NSB;
        const int b = wb / (GNUM - 1), g = wb % (GNUM - 1) + 1;
        const int gid = gap_idx[b * GNUM + g];
        const int lo = (gid - WINc > 0) ? gid - WINc : 0;
        const int hi = (gid + WINc < S_LEN - 1) ? gid + WINc : S_LEN - 1;
        const int n = hi - lo + 1;           // <= 25
        const int gsel = gid - lo;

        if (tid < 32)
            sh.w.wmf[tid] = (tid < n && mask[b * S_LEN + lo + tid] != 0) ? 1.f : 0.f;
        __syncthreads();
        if (tid == 0) {
            float d = 0.f;
            for (int i = 0; i < 25; ++i) d += sh.w.wmf[i];
            sh.w.rden = 1.f / d;
        }
        __syncthreads();
        const float rden = sh.w.rden;

        const float4* Wa4 = reinterpret_cast<const float4*>(W_att);
        const float4* Wm4 = reinterpret_cast<const float4*>(W_mod);

        float acc = 0.f;
        {
            const float4* base = reinterpret_cast<const float4*>(att)
                                 + ((size_t)b * S_LEN + lo) * (D8c/4) + tid;
            float4 mx = make_float4(0.f, 0.f, 0.f, 0.f);  // zero-clamped max
            float4 sm = make_float4(0.f, 0.f, 0.f, 0.f);
            float4 gv = make_float4(0.f, 0.f, 0.f, 0.f);
            #pragma unroll 5
            for (int i = 0; i < 25; ++i) {
                const int off = (i < n) ? i : 0;
                const float4 v = base[(size_t)off * (D8c/4)];
                const float w = sh.w.wmf[i];
                const float4 vm = f4scale(v, w);
                mx = f4max(mx, vm);
                sm = f4add(sm, vm);
                if (i == gsel) gv = v;
            }
            acc += dot4(gv, Wa4[tid]);
            acc += dot4(mx, Wa4[(D8c/4) + tid]) + dot4(sm, Wa4[2*(D8c/4) + tid]) * rden;
        }
        if (tid < D2c/4) {
            const float4* base = reinterpret_cast<const float4*>(mod)
                                 + ((size_t)b * S_LEN + lo) * (D2c/4) + tid;
            float4 mx = make_float4(0.f, 0.f, 0.f, 0.f);
            float4 sm = make_float4(0.f, 0.f, 0.f, 0.f);
            float4 gv = make_float4(0.f, 0.f, 0.f, 0.f);
            #pragma unroll 5
            for (int i = 0; i < 25; ++i) {
                const int off = (i < n) ? i : 0;
                const float4 v = base[(size_t)off * (D2c/4)];
                const float w = sh.w.wmf[i];
                const float4 vm = f4scale(v, w);
                mx = f4max(mx, vm);
                sm = f4add(sm, vm);
                if (i == gsel) gv = v;
            }
            acc += dot4(gv, Wm4[tid]);
            acc += dot4(mx, Wm4[(D2c/4) + tid]) + dot4(sm, Wm4[2*(D2c/4) + tid]) * rden;
        }

        sh.w.red[tid] = acc;
        __syncthreads();
        for (int off = 128; off > 0; off >>= 1) {
            if (tid < off) sh.w.red[tid] += sh.w.red[tid + off];
            __syncthreads();
        }
        if (tid == 0) winpart[b * GNUM + g] = sh.w.red[0];
    } else if (bid < NSB + NWB + BATCH * NCA) {
        // ---------------- att stream: 64 rows x 1024 ch, 2 load chains ----
        const int ab = bid - NSB - NWB;
        const int b = ab >> 6, ch = ab & 63;
        const float4* base = reinterpret_cast<const float4*>(att)
                             + ((size_t)b * S_LEN + ch * 64) * (D8c/4) + tid;
        float4 mx0 = make_float4(-INFINITY, -INFINITY, -INFINITY, -INFINITY);
        float4 mx1 = mx0;
        float4 sm0 = make_float4(0.f, 0.f, 0.f, 0.f);
        float4 sm1 = sm0;
        #pragma unroll 8
        for (int r = 0; r < 32; ++r) {
            const float4 v0 = base[(size_t)r * (D8c/4)];
            const float4 v1 = base[(size_t)(r + 32) * (D8c/4)];
            mx0 = f4max(mx0, v0); sm0 = f4add(sm0, v0);
            mx1 = f4max(mx1, v1); sm1 = f4add(sm1, v1);
        }
        const float4 mx = f4max(mx0, mx1);
        const float4 sm = f4add(sm0, sm1);
        unsigned* amax = attMaxU + (size_t)b * D8c + tid * 4;
        atomicMax(&amax[0], fmap(mx.x));
        atomicMax(&amax[1], fmap(mx.y));
        atomicMax(&amax[2], fmap(mx.z));
        atomicMax(&amax[3], fmap(mx.w));
        // distributed avg-dot: dot(sm, W_att_s[2*D8 + ch-slice])
        const float4 wsum = reinterpret_cast<const float4*>(W_att_s)[2*(D8c/4) + tid];
        sh.w.red[tid] = dot4(sm, wsum);
        __syncthreads();
        for (int off = 128; off > 0; off >>= 1) {
            if (tid < off) sh.w.red[tid] += sh.w.red[tid + off];
            __syncthreads();
        }
        if (tid == 0) atomicAdd(&sumdots[b], sh.w.red[0]);
    } else {
        // ---------------- mod stream: 4 subgroups x 64 rows, 2 chains -----
        const int mb = bid - NSB - NWB - BATCH * NCA;
        const int b = mb >> 4, ch = mb & 15;
        const int rg = tid >> 6, c4i = tid & 63;
        const float4* base = reinterpret_cast<const float4*>(mod)
                             + ((size_t)b * S_LEN + ch * 256 + rg * 64) * (D2c/4) + c4i;
        float4 mx0 = make_float4(-INFINITY, -INFINITY, -INFINITY, -INFINITY);
        float4 mx1 = mx0;
        float4 sm0 = make_float4(0.f, 0.f, 0.f, 0.f);
        float4 sm1 = sm0;
        #pragma unroll 8
        for (int r = 0; r < 32; ++r) {
            const float4 v0 = base[(size_t)r * (D2c/4)];
            const float4 v1 = base[(size_t)(r + 32) * (D2c/4)];
            mx0 = f4max(mx0, v0); sm0 = f4add(sm0, v0);
            mx1 = f4max(mx1, v1); sm1 = f4add(sm1, v1);
        }
        const float4 mx = f4max(mx0, mx1);
        const float4 sm = f4add(sm0, sm1);
        unsigned* mmax = modMaxU + (size_t)b * D2c + c4i * 4;
        atomicMax(&mmax[0], fmap(mx.x));
        atomicMax(&mmax[1], fmap(mx.y));
        atomicMax(&mmax[2], fmap(mx.z));
        atomicMax(&mmax[3], fmap(mx.w));
        const float4 wsum = reinterpret_cast<const float4*>(W_mod_s)[2*(D2c/4) + c4i];
        sh.w.red[tid] = dot4(sm, wsum);
        __syncthreads();
        for (int off = 128; off > 0; off >>= 1) {
            if (tid < off) sh.w.red[tid] += sh.w.red[tid + off];
            __syncthreads();
        }
        if (tid == 0) atomicAdd(&sumdots[BATCH + b], sh.w.red[0]);
    }
}

// ---------------------------------------------------------------------------
// K2: per-batch: q-side dots, softmaxes, att2, tiny g0 combine, output.
// ---------------------------------------------------------------------------
__global__ __launch_bounds__(256) void k2_kernel(
    const float* __restrict__ att, const float* __restrict__ mod,
    const float* __restrict__ q_enc,
    const int* __restrict__ gap_idx, const int* __restrict__ mask,
    const int* __restrict__ q_mask,
    const float* __restrict__ q_w, const float* __restrict__ att_bias,
    const float* __restrict__ W_att2, const float* __restrict__ W_att_s2,
    const float* __restrict__ W_att_s, const float* __restrict__ W_mod_s,
    const float* __restrict__ b_att, const float* __restrict__ b_mod,
    const float* __restrict__ b_att2,
    const float* __restrict__ b_att_s, const float* __restrict__ b_mod_s,
    const float* __restrict__ b_att_s2,
    const unsigned* __restrict__ attMaxU, const unsigned* __restrict__ modMaxU,
    const float* __restrict__ sumdots,
    const float* __restrict__ s2v_ws, const float* __restrict__ vv_ws,
    const float* __restrict__ m_ws, const float* __restrict__ s0uc_ws,
    const float* __restrict__ winpart,
    float* __restrict__ out)
{
    const int b = blockIdx.x;
    const int tid = threadIdx.x;

    __shared__ float s_sh[GNUM][QNUM];
    __shared__ float sm1[GNUM][QNUM];
    __shared__ float sm2[GNUM][QNUM];
    __shared__ float ssm[GNUM][GNUM];
    __shared__ float pq[3][4][QNUM];
    __shared__ float s1[QNUM], u0[QNUM], u1[QNUM];
    __shared__ float s0g[GNUM], ucg[GNUM], att2v[GNUM];
    __shared__ float red[256];
    __shared__ float rdensh;

    // ---- Phase Q: s1/u0/u1 via (q, d-quarter) partials -------------------
    {
        const int q = tid & 63, p = tid >> 6;
        if (q < QNUM) {
            const float4* qr = reinterpret_cast<const float4*>(q_enc)
                               + ((size_t)b * QNUM + q) * (D2c/4) + p * 16;
            const float4* w1 = reinterpret_cast<const float4*>(q_w) + p * 16;
            const float4* w2 = reinterpret_cast<const float4*>(W_att_s2) + (D2c/4) + p * 16;
            const float4* w3 = reinterpret_cast<const float4*>(W_att2)   + (D2c/4) + p * 16;
            float a1 = 0.f, a2 = 0.f, a3 = 0.f;
            #pragma unroll
            for (int i = 0; i < 16; ++i) {
                const float4 v = qr[i];
                a1 += dot4(v, w1[i]);
                a2 += dot4(v, w2[i]);
                a3 += dot4(v, w3[i]);
            }
            pq[0][p][q] = a1; pq[1][p][q] = a2; pq[2][p][q] = a3;
        }
    }
    if (tid < GNUM) {
        s0g[tid] = s0uc_ws[((size_t)b * GNUM + tid) * 2 + 0];
        ucg[tid] = s0uc_ws[((size_t)b * GNUM + tid) * 2 + 1];
    }
    __syncthreads();
    if (tid < QNUM) {
        s1[tid] = pq[0][0][tid] + pq[0][1][tid] + pq[0][2][tid] + pq[0][3][tid];
        u0[tid] = pq[1][0][tid] + pq[1][1][tid] + pq[1][2][tid] + pq[1][3][tid];
        u1[tid] = pq[2][0][tid] + pq[2][1][tid] + pq[2][2][tid] + pq[2][3][tid];
    }
    __syncthreads();

    // ---- build s ----------------------------------------------------------
    const float bias = att_bias[0];
    for (int i = tid; i < GNUM * QNUM; i += 256) {
        const int g = i / QNUM, q = i % QNUM;
        s_sh[g][q] = s0g[g] + s1[q] + s2v_ws[((size_t)b * GNUM + g) * QNUM + q] + bias;
    }
    __syncthreads();

    // ---- softmaxes --------------------------------------------------------
    if (tid < QNUM) {
        const int q = tid;
        float mxv = -1e30f;
        for (int g = 0; g < GNUM; ++g) mxv = fmaxf(mxv, s_sh[g][q]);
        float sum = 0.f;
        for (int g = 0; g < GNUM; ++g) {
            const float e = __expf(s_sh[g][q] - mxv);
            sm2[g][q] = e;
            sum += e;
        }
        const float inv = 1.f / sum;
        for (int g = 0; g < GNUM; ++g) sm2[g][q] *= inv;
    } else if (tid >= 64 && tid < 64 + GNUM) {
        const int g = tid - 64;
        float mxv = -1e30f;
        for (int q = 0; q < QNUM; ++q)
            if (q_mask[b * QNUM + q]) mxv = fmaxf(mxv, s_sh[g][q]);
        float sum = 0.f;
        for (int q = 0; q < QNUM; ++q) {
            const float e = q_mask[b * QNUM + q] ? __expf(s_sh[g][q] - mxv) : 0.f;
            sm1[g][q] = e;
            sum += e;
        }
        const float inv = 1.f / sum;
        for (int q = 0; q < QNUM; ++q) sm1[g][q] *= inv;
    }
    __syncthreads();

    // ---- ss*m: thread-per-(g,k) -------------------------------------------
    for (int i = tid; i < GNUM * GNUM; i += 256) {
        const int g = i / GNUM, k = i % GNUM;
        float t = 0.f;
        for (int q = 0; q < QNUM; ++q) t += sm1[g][q] * sm2[k][q];
        ssm[g][k] = t * m_ws[((size_t)b * GNUM + g) * GNUM + k];
    }
    __syncthreads();

    // ---- att2 logit per g ---------------------------------------------------
    if (tid < GNUM) {
        const int g = tid;
        const float* uu = (g == 0) ? u0 : u1;
        float acc = ucg[g];
        for (int q = 0; q < QNUM; ++q)
            acc += sm1[g][q] * (uu[q] + vv_ws[((size_t)b * GNUM + g) * QNUM + q]);
        for (int k = 0; k < GNUM; ++k) acc += ssm[g][k];
        att2v[g] = acc;
    }

    // ---- Part 2: denom0 + tiny g0 combine + output --------------------------
    float cnt = 0.f;
    for (int s = tid; s < S_LEN; s += 256) cnt += (mask[b * S_LEN + s] != 0) ? 1.f : 0.f;
    red[tid] = cnt;
    __syncthreads();
    for (int off = 128; off > 0; off >>= 1) {
        if (tid < off) red[tid] += red[tid + off];
        __syncthreads();
    }
    if (tid == 0) rdensh = 1.f / red[0];
    __syncthreads();
    const float rden0 = rdensh;

    const int gid0 = gap_idx[b * GNUM];
    const float4* Wa4 = reinterpret_cast<const float4*>(W_att_s);
    const float4* Wm4 = reinterpret_cast<const float4*>(W_mod_s);

    float acc = 0.f;
    {
        const uint4 mu = reinterpret_cast<const uint4*>(attMaxU + (size_t)b * D8c)[tid];
        const float4 mx = make_float4(funmap(mu.x), funmap(mu.y), funmap(mu.z), funmap(mu.w));
        acc += dot4(mx, Wa4[(D8c/4) + tid]);
        const float4 ar = reinterpret_cast<const float4*>(att)[((size_t)b * S_LEN + gid0) * (D8c/4) + tid];
        acc += dot4(ar, Wa4[tid]);
    }
    if (tid < D2c/4) {
        const uint4 mu = reinterpret_cast<const uint4*>(modMaxU + (size_t)b * D2c)[tid];
        const float4 mx = make_float4(funmap(mu.x), funmap(mu.y), funmap(mu.z), funmap(mu.w));
        acc += dot4(mx, Wm4[(D2c/4) + tid]);
        const float4 mr = reinterpret_cast<const float4*>(mod)[((size_t)b * S_LEN + gid0) * (D2c/4) + tid];
        acc += dot4(mr, Wm4[tid]);
    }

    __syncthreads();
    red[tid] = acc;
    __syncthreads();
    for (int off = 128; off > 0; off >>= 1) {
        if (tid < off) red[tid] += red[tid + off];
        __syncthreads();
    }
    if (tid == 0) {
        const float avgpart = (sumdots[b] + sumdots[BATCH + b]) * rden0;
        out[b * GNUM] = red[0] + avgpart + att2v[0] + b_att_s[0] + b_mod_s[0] + b_att_s2[0];
    } else if (tid < GNUM) {
        out[b * GNUM + tid] = winpart[b * GNUM + tid] + att2v[tid]
                              + b_att[0] + b_mod[0] + b_att2[0];
    }
}

// ---------------------------------------------------------------------------
extern "C" void kernel_launch(void* const* d_in, const int* in_sizes, int n_in,
                              void* d_out, int out_size, void* d_ws, size_t ws_size,
                              hipStream_t stream)
{
    const float* att      = (const float*)d_in[0];
    const float* mod      = (const float*)d_in[1];
    const float* q_enc    = (const float*)d_in[2];
    const int*   gap_idx  = (const int*)  d_in[3];
    const int*   mask     = (const int*)  d_in[4];
    const int*   q_mask   = (const int*)  d_in[5];
    const float* c_w      = (const float*)d_in[6];
    const float* q_w      = (const float*)d_in[7];
    const float* cq_w     = (const float*)d_in[8];
    const float* att_bias = (const float*)d_in[9];
    const float* W_att    = (const float*)d_in[10];
    const float* b_att    = (const float*)d_in[11];
    const float* W_mod    = (const float*)d_in[12];
    const float* b_mod    = (const float*)d_in[13];
    const float* W_att2   = (const float*)d_in[14];
    const float* b_att2   = (const float*)d_in[15];
    const float* W_att_s  = (const float*)d_in[16];
    const float* b_att_s  = (const float*)d_in[17];
    const float* W_mod_s  = (const float*)d_in[18];
    const float* b_mod_s  = (const float*)d_in[19];
    const float* W_att_s2 = (const float*)d_in[20];
    const float* b_att_s2 = (const float*)d_in[21];

    float* out = (float*)d_out;

    // ws layout: atomic region first (zeroed every call), then k1->k2 arrays
    unsigned* attMaxU = (unsigned*)d_ws;                              // 16*1024
    unsigned* modMaxU = attMaxU + (size_t)BATCH * D8c;                // 16*256
    float*    sumdots = (float*)(modMaxU + (size_t)BATCH * D2c);      // 32
    float*    s2v_ws  = sumdots + 32;                                 // 384*48
    float*    vv_ws   = s2v_ws + (size_t)NSB * QNUM;                  // 384*48
    float*    m_ws    = vv_ws  + (size_t)NSB * QNUM;                  // 384*24
    float*    s0uc_ws = m_ws   + (size_t)NSB * GNUM;                  // 768
    float*    winpart = s0uc_ws + (size_t)NSB * 2;                    // 384

    const size_t atomicBytes = ((size_t)BATCH * D8c + (size_t)BATCH * D2c + 32) * 4;
    (void)hipMemsetAsync(d_ws, 0, atomicBytes, stream);  // mapped-max sentinel + 0.f sums

    const int grid1 = NSB + NWB + BATCH*NCA + BATCH*NCM;              // 2032

    k1_kernel<<<grid1, 256, 0, stream>>>(
        att, mod, q_enc, gap_idx, mask,
        c_w, cq_w, W_att2, W_att_s2, W_att, W_mod, W_att_s, W_mod_s,
        attMaxU, modMaxU, sumdots,
        s2v_ws, vv_ws, m_ws, s0uc_ws, winpart);

    k2_kernel<<<BATCH, 256, 0, stream>>>(
        att, mod, q_enc, gap_idx, mask, q_mask,
        q_w, att_bias, W_att2, W_att_s2,
        W_att_s, W_mod_s, b_att, b_mod, b_att2,
        b_att_s, b_mod_s, b_att_s2,
        attMaxU, modMaxU, sumdots,
        s2v_ws, vv_ws, m_ws, s0uc_ws, winpart, out);
}